// Round 12
// baseline (106.139 us; speedup 1.0000x reference)
//
#include <hip/hip_runtime.h>
#include <math.h>

#define NTOK 16384
#define DIM  4096
#define NEXP 64
#define KS   4                // K-split factor
#define KSL  (DIM / KS)       // 1024 k per slice
#define BK   32               // k per chunk
#define NCH  (KSL / BK)       // 32 chunks
#define BM   64               // tokens per block (2x2 waves of 32x32)

typedef __fp16 f16x8  __attribute__((ext_vector_type(8)));
typedef __fp16 f16x2  __attribute__((ext_vector_type(2)));
typedef float  f32x16 __attribute__((ext_vector_type(16)));

__device__ __forceinline__ void gl_lds16(const void* g, void* l) {
  __builtin_amdgcn_global_load_lds(
      (const __attribute__((address_space(1))) void*)g,
      (__attribute__((address_space(3))) void*)l, 16, 0, 0);
}

// ---- prep: split W (fp32) into 2 fp16 planes (RNE hi, RNE residual) ----
__global__ __launch_bounds__(256) void split_w(
    const float* __restrict__ W,
    __fp16* __restrict__ Wh,
    __fp16* __restrict__ Wl)
{
  const int i = blockIdx.x * 256 + threadIdx.x;   // grid covers 64*4096
  const float w = W[i];
  const __fp16 h = (__fp16)w;                     // RNE
  const float r = w - (float)h;                   // exact
  Wh[i] = h;
  Wl[i] = (__fp16)r;                              // RNE, residual ~2^-24|w|
}

// ---- phase 1: 32x32x16 MFMA; 3-buffer 2-ahead gl_lds pipeline,
// counted vmcnt(4) + ONE s_barrier per chunk (T3/T4) ----
__global__ __launch_bounds__(256, 3) void router_mfma(
    const float* __restrict__ tokens,
    const __fp16* __restrict__ Wh,
    const __fp16* __restrict__ Wl,
    float* __restrict__ partial)   // [KS][NTOK][NEXP]
{
  __shared__ float  As[3][BM * BK];     // 3 x 8 KB
  __shared__ __fp16 Bh[3][NEXP * BK];   // 3 x 4 KB
  __shared__ __fp16 Bl[3][NEXP * BK];   // 3 x 4 KB   -> 48 KB

  const int tid  = threadIdx.x;
  const int wid  = tid >> 6;
  const int lane = tid & 63;
  const int rc2  = lane & 31;           // MFMA row/col within 32
  const int q2   = lane >> 5;           // k-half
  const int wr   = wid >> 1;            // token 32-half
  const int ec   = wid & 1;             // expert 32-half
  const int s    = blockIdx.x & (KS - 1);
  const int tb   = (blockIdx.x >> 2) * BM;   // block token base
  const int kbase = s * KSL;

  // ---- staging sources (pre-swizzled global, linear LDS dest: G21) ----
  // A: 2 instrs/wave, each 8 rows x 128B; row key = row&7 (= lane>>3 here)
  const int a_tl = lane >> 3, a_j = lane & 7;
  const float* asrc0 = tokens + (size_t)(tb + 16 * wid + a_tl) * DIM + kbase
                       + ((a_j ^ a_tl) << 2);
  const float* asrc1 = asrc0 + (size_t)8 * DIM;
  // B: 1 instr/plane/wave, 16 rows x 64B; key = e&3
  const int b_el = lane >> 2, b_j = lane & 3;
  const size_t boff = (size_t)(16 * wid + b_el) * DIM + kbase
                      + ((b_j ^ (b_el & 3)) << 3);
  const __fp16* bsrc_h = Wh + boff;
  const __fp16* bsrc_l = Wl + boff;

#define STAGE(buf, c) {                                  \
    const int ko = (c) * BK;                             \
    gl_lds16(asrc0 + ko, &As[buf][(16 * wid) * 32]);     \
    gl_lds16(asrc1 + ko, &As[buf][(16 * wid + 8) * 32]); \
    gl_lds16(bsrc_h + ko, &Bh[buf][(16 * wid) * 32]);    \
    gl_lds16(bsrc_l + ko, &Bl[buf][(16 * wid) * 32]);    \
  }

  f32x16 acc = {0,0,0,0, 0,0,0,0, 0,0,0,0, 0,0,0,0};

  // read-side constants
  const int akey = rc2 & 7;             // A row has 8 16B units
  const int bkey = rc2 & 3;             // B row has 4 16B units
  const int Arow = (32 * wr + rc2) * 32;
  const int Brow = (32 * ec + rc2) * 32;

#define KSTEP(buf, kk) {                                                     \
    const int u0 = 4 * (kk) + 2 * q2;                                        \
    const float4 a0 = *(const float4*)(&As[buf][Arow + ((u0    ) ^ akey) * 4]); \
    const float4 a1 = *(const float4*)(&As[buf][Arow + ((u0 + 1) ^ akey) * 4]); \
    const int ub = ((2 * (kk) + q2) ^ bkey) * 8;                             \
    const f16x8 bhv = *(const f16x8*)(&Bh[buf][Brow + ub]);                  \
    const f16x8 blv = *(const f16x8*)(&Bl[buf][Brow + ub]);                  \
    const f16x2 h0 = __builtin_amdgcn_cvt_pkrtz(a0.x, a0.y);                 \
    const f16x2 h1 = __builtin_amdgcn_cvt_pkrtz(a0.z, a0.w);                 \
    const f16x2 h2 = __builtin_amdgcn_cvt_pkrtz(a1.x, a1.y);                 \
    const f16x2 h3 = __builtin_amdgcn_cvt_pkrtz(a1.z, a1.w);                 \
    const f16x2 m0 = __builtin_amdgcn_cvt_pkrtz(a0.x - (float)h0[0],         \
                                                a0.y - (float)h0[1]);        \
    const f16x2 m1 = __builtin_amdgcn_cvt_pkrtz(a0.z - (float)h1[0],         \
                                                a0.w - (float)h1[1]);        \
    const f16x2 m2 = __builtin_amdgcn_cvt_pkrtz(a1.x - (float)h2[0],         \
                                                a1.y - (float)h2[1]);        \
    const f16x2 m3 = __builtin_amdgcn_cvt_pkrtz(a1.z - (float)h3[0],         \
                                                a1.w - (float)h3[1]);        \
    const f16x8 Ah = {h0[0],h0[1],h1[0],h1[1],h2[0],h2[1],h3[0],h3[1]};      \
    const f16x8 Am = {m0[0],m0[1],m1[0],m1[1],m2[0],m2[1],m3[0],m3[1]};      \
    acc = __builtin_amdgcn_mfma_f32_32x32x16_f16(Ah, bhv, acc, 0, 0, 0);     \
    acc = __builtin_amdgcn_mfma_f32_32x32x16_f16(Ah, blv, acc, 0, 0, 0);     \
    acc = __builtin_amdgcn_mfma_f32_32x32x16_f16(Am, bhv, acc, 0, 0, 0);     \
  }

#define COMP(buf) { KSTEP(buf, 0); KSTEP(buf, 1); }

#define VM(n) asm volatile("s_waitcnt vmcnt(" #n ")" ::: "memory")
#define BAR() __builtin_amdgcn_s_barrier()

  // prologue: 2 chunks in flight
  STAGE(0, 0);
  STAGE(1, 1);

  // slots 0..29: {vmcnt(4); barrier; stage 2-ahead; compute}.
  // At slot c's VM(4): in-flight = S(c)rem + S(c+1)(4) -> S(c) drained,
  // S(c+1) stays airborne. Each stage gets ~2 slots of flight.
  // STAGE(buf) is issued right after the barrier that retired buf's readers.
  for (int i = 0; i < 10; ++i) {
    const int c = 3 * i;
    VM(4); BAR(); STAGE(2, c + 2); COMP(0);
    VM(4); BAR(); STAGE(0, c + 3); COMP(1);
    VM(4); BAR(); STAGE(1, c + 4); COMP(2);
  }
  // tail: chunk 30 (buf0), chunk 31 (buf1)
  VM(4); BAR(); COMP(0);
  VM(0); BAR(); COMP(1);

#undef STAGE
#undef COMP
#undef KSTEP
#undef VM
#undef BAR

  // write partial logits: D col = rc2 (expert within 32),
  // D row = (reg&3) + 8*(reg>>2) + 4*q2 (token within 32)  [m74-verified]
  float* P = partial + ((size_t)s * NTOK + tb + 32 * wr) * NEXP + 32 * ec;
  #pragma unroll
  for (int reg = 0; reg < 16; ++reg) {
    const int row = (reg & 3) + 8 * (reg >> 2) + 4 * q2;
    P[(size_t)row * NEXP + rc2] = acc[reg];
  }
}

// ---- phase 2: reduce partials, softmax + top-2 ----
__global__ __launch_bounds__(64) void router_finish(
    const float* __restrict__ partial,
    float* __restrict__ out)
{
  const int t = blockIdx.x * 64 + threadIdx.x;

  float l[NEXP];
  const float* p0 = partial + (size_t)t * NEXP;
  #pragma unroll
  for (int qq = 0; qq < 16; ++qq) {
    const float4 v = *(const float4*)(p0 + qq * 4);
    l[qq*4+0] = v.x; l[qq*4+1] = v.y; l[qq*4+2] = v.z; l[qq*4+3] = v.w;
  }
  #pragma unroll
  for (int s = 1; s < KS; ++s) {
    const float* p = partial + ((size_t)s * NTOK + t) * NEXP;
    #pragma unroll
    for (int qq = 0; qq < 16; ++qq) {
      const float4 v = *(const float4*)(p + qq * 4);
      l[qq*4+0] += v.x; l[qq*4+1] += v.y; l[qq*4+2] += v.z; l[qq*4+3] += v.w;
    }
  }

  // top-2, lax.top_k tie-break (ascending scan with strict > keeps lower idx)
  float t1v = l[0]; int t1i = 0;
  float t2v = -INFINITY; int t2i = NEXP;
  #pragma unroll
  for (int e = 1; e < NEXP; ++e) {
    const float v = l[e];
    if (v > t1v) { t2v = t1v; t2i = t1i; t1v = v; t1i = e; }
    else if (v > t2v) { t2v = v; t2i = e; }
  }

  float ssum = 0.f;
  #pragma unroll
  for (int e = 0; e < NEXP; ++e) ssum += expf(l[e] - t1v);

  const float inv = 1.0f / ssum;
  out[t * 2 + 0] = inv;
  out[t * 2 + 1] = expf(t2v - t1v) * inv;
  out[2 * NTOK + t * 2 + 0] = (float)t1i;
  out[2 * NTOK + t * 2 + 1] = (float)t2i;
}

extern "C" void kernel_launch(void* const* d_in, const int* in_sizes, int n_in,
                              void* d_out, int out_size, void* d_ws, size_t ws_size,
                              hipStream_t stream) {
  const float* tokens = (const float*)d_in[0];
  const float* W      = (const float*)d_in[1];
  float* out          = (float*)d_out;

  __fp16* Wh = (__fp16*)d_ws;
  __fp16* Wl = Wh + (size_t)NEXP * DIM;
  float* partial = (float*)((char*)d_ws + (size_t)2 * NEXP * DIM * sizeof(__fp16));

  split_w<<<(NEXP * DIM) / 256, 256, 0, stream>>>(W, Wh, Wl);
  router_mfma<<<(NTOK / BM) * KS, 256, 0, stream>>>(tokens, Wh, Wl, partial);
  router_finish<<<NTOK / 64, 64, 0, stream>>>(partial, out);
}

// Round 13
// 83.729 us; speedup vs baseline: 1.2677x; 1.2677x over previous
//
#include <hip/hip_runtime.h>
#include <math.h>

#define NTOK 16384
#define DIM  4096
#define NEXP 64
#define KS   4                // K-split factor
#define KSL  (DIM / KS)       // 1024 k per slice
#define BK   32               // k per chunk
#define NCH  (KSL / BK)       // 32 chunks
#define BM   64               // tokens per block (2x2 waves of 32x32)

typedef __fp16 f16x8  __attribute__((ext_vector_type(8)));
typedef __fp16 f16x2  __attribute__((ext_vector_type(2)));
typedef float  f32x16 __attribute__((ext_vector_type(16)));

__device__ __forceinline__ void gl_lds16(const void* g, void* l) {
  __builtin_amdgcn_global_load_lds(
      (const __attribute__((address_space(1))) void*)g,
      (__attribute__((address_space(3))) void*)l, 16, 0, 0);
}

// ---- prep: split W (fp32) into 2 fp16 planes (RNE hi, RNE residual) ----
__global__ __launch_bounds__(256) void split_w(
    const float* __restrict__ W,
    __fp16* __restrict__ Wh,
    __fp16* __restrict__ Wl)
{
  const int i = blockIdx.x * 256 + threadIdx.x;   // grid covers 64*4096
  const float w = W[i];
  const __fp16 h = (__fp16)w;                     // RNE
  const float r = w - (float)h;                   // exact
  Wh[i] = h;
  Wl[i] = (__fp16)r;                              // RNE, residual ~2^-24|w|
}

// ---- phase 1: 32x32x16 MFMA; BK=32 double-buffer, r7 sync, 4 blocks/CU ----
__global__ __launch_bounds__(256, 4) void router_mfma(
    const float* __restrict__ tokens,
    const __fp16* __restrict__ Wh,
    const __fp16* __restrict__ Wl,
    float* __restrict__ partial)   // [KS][NTOK][NEXP]
{
  __shared__ float  As[2][BM * BK];     // 2 x 8 KB
  __shared__ __fp16 Bh[2][NEXP * BK];   // 2 x 4 KB
  __shared__ __fp16 Bl[2][NEXP * BK];   // 2 x 4 KB   -> 32 KB

  const int tid  = threadIdx.x;
  const int wid  = tid >> 6;
  const int lane = tid & 63;
  const int rc2  = lane & 31;           // MFMA row/col within 32
  const int q2   = lane >> 5;           // k-half
  const int wr   = wid >> 1;            // token 32-half
  const int ec   = wid & 1;             // expert 32-half
  const int s    = blockIdx.x & (KS - 1);
  const int tb   = (blockIdx.x >> 2) * BM;   // block token base
  const int kbase = s * KSL;

  // ---- staging sources (pre-swizzled global, linear LDS dest: G21) ----
  // A: 2 instrs/wave, each 8 rows x 128B; key = row&7 (= lane>>3 here)
  const int a_tl = lane >> 3, a_j = lane & 7;
  const float* asrc0 = tokens + (size_t)(tb + 16 * wid + a_tl) * DIM + kbase
                       + ((a_j ^ a_tl) << 2);
  const float* asrc1 = asrc0 + (size_t)8 * DIM;
  // B: 1 instr/plane/wave, 16 rows x 64B; key = e&3
  const int b_el = lane >> 2, b_j = lane & 3;
  const size_t boff = (size_t)(16 * wid + b_el) * DIM + kbase
                      + ((b_j ^ (b_el & 3)) << 3);
  const __fp16* bsrc_h = Wh + boff;
  const __fp16* bsrc_l = Wl + boff;

#define STAGE(buf, c) {                                  \
    const int ko = (c) * BK;                             \
    gl_lds16(asrc0 + ko, &As[buf][(16 * wid) * 32]);     \
    gl_lds16(asrc1 + ko, &As[buf][(16 * wid + 8) * 32]); \
    gl_lds16(bsrc_h + ko, &Bh[buf][(16 * wid) * 32]);    \
    gl_lds16(bsrc_l + ko, &Bl[buf][(16 * wid) * 32]);    \
  }

  f32x16 acc = {0,0,0,0, 0,0,0,0, 0,0,0,0, 0,0,0,0};

  // read-side constants
  const int akey = rc2 & 7;             // A row has 8 16B units
  const int bkey = rc2 & 3;             // B row has 4 16B units
  const int Arow = (32 * wr + rc2) * 32;
  const int Brow = (32 * ec + rc2) * 32;

#define KSTEP(buf, kk) {                                                     \
    const int u0 = 4 * (kk) + 2 * q2;                                        \
    const float4 a0 = *(const float4*)(&As[buf][Arow + ((u0    ) ^ akey) * 4]); \
    const float4 a1 = *(const float4*)(&As[buf][Arow + ((u0 + 1) ^ akey) * 4]); \
    const int ub = ((2 * (kk) + q2) ^ bkey) * 8;                             \
    const f16x8 bhv = *(const f16x8*)(&Bh[buf][Brow + ub]);                  \
    const f16x8 blv = *(const f16x8*)(&Bl[buf][Brow + ub]);                  \
    const f16x2 h0 = __builtin_amdgcn_cvt_pkrtz(a0.x, a0.y);                 \
    const f16x2 h1 = __builtin_amdgcn_cvt_pkrtz(a0.z, a0.w);                 \
    const f16x2 h2 = __builtin_amdgcn_cvt_pkrtz(a1.x, a1.y);                 \
    const f16x2 h3 = __builtin_amdgcn_cvt_pkrtz(a1.z, a1.w);                 \
    const f16x2 m0 = __builtin_amdgcn_cvt_pkrtz(a0.x - (float)h0[0],         \
                                                a0.y - (float)h0[1]);        \
    const f16x2 m1 = __builtin_amdgcn_cvt_pkrtz(a0.z - (float)h1[0],         \
                                                a0.w - (float)h1[1]);        \
    const f16x2 m2 = __builtin_amdgcn_cvt_pkrtz(a1.x - (float)h2[0],         \
                                                a1.y - (float)h2[1]);        \
    const f16x2 m3 = __builtin_amdgcn_cvt_pkrtz(a1.z - (float)h3[0],         \
                                                a1.w - (float)h3[1]);        \
    const f16x8 Ah = {h0[0],h0[1],h1[0],h1[1],h2[0],h2[1],h3[0],h3[1]};      \
    const f16x8 Am = {m0[0],m0[1],m1[0],m1[1],m2[0],m2[1],m3[0],m3[1]};      \
    acc = __builtin_amdgcn_mfma_f32_32x32x16_f16(Ah, bhv, acc, 0, 0, 0);     \
    acc = __builtin_amdgcn_mfma_f32_32x32x16_f16(Ah, blv, acc, 0, 0, 0);     \
    acc = __builtin_amdgcn_mfma_f32_32x32x16_f16(Am, bhv, acc, 0, 0, 0);     \
  }

#define COMP(buf) { KSTEP(buf, 0); KSTEP(buf, 1); }

  // prologue
  STAGE(0, 0);
  __syncthreads();

  // main loop: r7-proven 1-barrier-per-chunk double buffer
  for (int c = 0; c < NCH; c += 2) {
    if (c + 1 < NCH) STAGE(1, c + 1);
    COMP(0);
    __syncthreads();
    if (c + 2 < NCH) STAGE(0, c + 2);
    COMP(1);
    __syncthreads();
  }
#undef STAGE
#undef COMP
#undef KSTEP

  // write partial logits: D col = rc2 (expert within 32),
  // D row = (reg&3) + 8*(reg>>2) + 4*q2 (token within 32)  [m74-verified]
  float* P = partial + ((size_t)s * NTOK + tb + 32 * wr) * NEXP + 32 * ec;
  #pragma unroll
  for (int reg = 0; reg < 16; ++reg) {
    const int row = (reg & 3) + 8 * (reg >> 2) + 4 * q2;
    P[(size_t)row * NEXP + rc2] = acc[reg];
  }
}

// ---- phase 2: reduce partials, softmax + top-2 ----
__global__ __launch_bounds__(256) void router_finish(
    const float* __restrict__ partial,
    float* __restrict__ out)
{
  const int t = blockIdx.x * 256 + threadIdx.x;

  float l[NEXP];
  const float* p0 = partial + (size_t)t * NEXP;
  #pragma unroll
  for (int qq = 0; qq < 16; ++qq) {
    const float4 v = *(const float4*)(p0 + qq * 4);
    l[qq*4+0] = v.x; l[qq*4+1] = v.y; l[qq*4+2] = v.z; l[qq*4+3] = v.w;
  }
  #pragma unroll
  for (int s = 1; s < KS; ++s) {
    const float* p = partial + ((size_t)s * NTOK + t) * NEXP;
    #pragma unroll
    for (int qq = 0; qq < 16; ++qq) {
      const float4 v = *(const float4*)(p + qq * 4);
      l[qq*4+0] += v.x; l[qq*4+1] += v.y; l[qq*4+2] += v.z; l[qq*4+3] += v.w;
    }
  }

  // top-2, lax.top_k tie-break (ascending scan with strict > keeps lower idx)
  float t1v = l[0]; int t1i = 0;
  float t2v = -INFINITY; int t2i = NEXP;
  #pragma unroll
  for (int e = 1; e < NEXP; ++e) {
    const float v = l[e];
    if (v > t1v) { t2v = t1v; t2i = t1i; t1v = v; t1i = e; }
    else if (v > t2v) { t2v = v; t2i = e; }
  }

  float ssum = 0.f;
  #pragma unroll
  for (int e = 0; e < NEXP; ++e) ssum += expf(l[e] - t1v);

  const float inv = 1.0f / ssum;
  out[t * 2 + 0] = inv;
  out[t * 2 + 1] = expf(t2v - t1v) * inv;
  out[2 * NTOK + t * 2 + 0] = (float)t1i;
  out[2 * NTOK + t * 2 + 1] = (float)t2i;
}

extern "C" void kernel_launch(void* const* d_in, const int* in_sizes, int n_in,
                              void* d_out, int out_size, void* d_ws, size_t ws_size,
                              hipStream_t stream) {
  const float* tokens = (const float*)d_in[0];
  const float* W      = (const float*)d_in[1];
  float* out          = (float*)d_out;

  __fp16* Wh = (__fp16*)d_ws;
  __fp16* Wl = Wh + (size_t)NEXP * DIM;
  float* partial = (float*)((char*)d_ws + (size_t)2 * NEXP * DIM * sizeof(__fp16));

  split_w<<<(NEXP * DIM) / 256, 256, 0, stream>>>(W, Wh, Wl);
  router_mfma<<<(NTOK / BM) * KS, 256, 0, stream>>>(tokens, Wh, Wl, partial);
  router_finish<<<NTOK / 256, 256, 0, stream>>>(partial, out);
}

// Round 14
// 83.070 us; speedup vs baseline: 1.2777x; 1.0079x over previous
//
#include <hip/hip_runtime.h>
#include <math.h>

#define NTOK 16384
#define DIM  4096
#define NEXP 64
#define KS   4                // K-split factor
#define KSL  (DIM / KS)       // 1024 k per slice
#define BK   32               // k per chunk
#define NCH  (KSL / BK)       // 32 chunks
#define BM   128              // tokens per block (4 waves x 32 tokens)

typedef __fp16 f16x8  __attribute__((ext_vector_type(8)));
typedef __fp16 f16x2  __attribute__((ext_vector_type(2)));
typedef float  f32x16 __attribute__((ext_vector_type(16)));

__device__ __forceinline__ void gl_lds16(const void* g, void* l) {
  __builtin_amdgcn_global_load_lds(
      (const __attribute__((address_space(1))) void*)g,
      (__attribute__((address_space(3))) void*)l, 16, 0, 0);
}

// ---- prep: split W (fp32) into 2 fp16 planes (RNE hi, RNE residual) ----
__global__ __launch_bounds__(256) void split_w(
    const float* __restrict__ W,
    __fp16* __restrict__ Wh,
    __fp16* __restrict__ Wl)
{
  const int i = blockIdx.x * 256 + threadIdx.x;   // grid covers 64*4096
  const float w = W[i];
  const __fp16 h = (__fp16)w;                     // RNE
  const float r = w - (float)h;                   // exact
  Wh[i] = h;
  Wl[i] = (__fp16)r;                              // RNE, residual ~2^-24|w|
}

// ---- phase 1: 32x32x16 MFMA; wave = 32 unique tokens x 64 experts
// (A-split VALU deduplicated); r7-proven dbuf sync ----
__global__ __launch_bounds__(256, 2) void router_mfma(
    const float* __restrict__ tokens,
    const __fp16* __restrict__ Wh,
    const __fp16* __restrict__ Wl,
    float* __restrict__ partial)   // [KS][NTOK][NEXP]
{
  __shared__ float  As[2][BM * BK];     // 2 x 16 KB
  __shared__ __fp16 Bh[2][NEXP * BK];   // 2 x 4 KB
  __shared__ __fp16 Bl[2][NEXP * BK];   // 2 x 4 KB   -> 48 KB

  const int tid  = threadIdx.x;
  const int wid  = tid >> 6;
  const int lane = tid & 63;
  const int rc2  = lane & 31;           // MFMA row/col within 32
  const int q2   = lane >> 5;           // k-half
  const int s    = blockIdx.x & (KS - 1);
  const int tb   = (blockIdx.x >> 2) * BM;   // block token base
  const int kbase = s * KSL;

  // ---- staging sources (pre-swizzled global, linear LDS dest: G21) ----
  // A: wave stages its own 32 rows as 4 instrs x 8 rows x 128B; key = row&7
  const int a_tl = lane >> 3, a_j = lane & 7;
  const float* asrc = tokens + (size_t)(tb + 32 * wid + a_tl) * DIM + kbase
                      + ((a_j ^ a_tl) << 2);
  // B: 1 instr/plane/wave, 16 rows x 64B; key = e&3
  const int b_el = lane >> 2, b_j = lane & 3;
  const size_t boff = (size_t)(16 * wid + b_el) * DIM + kbase
                      + ((b_j ^ (b_el & 3)) << 3);
  const __fp16* bsrc_h = Wh + boff;
  const __fp16* bsrc_l = Wl + boff;

#define STAGE(buf, c) {                                               \
    const int ko = (c) * BK;                                          \
    gl_lds16(asrc + ko,                  &As[buf][(32*wid     ) * 32]); \
    gl_lds16(asrc + (size_t) 8*DIM + ko, &As[buf][(32*wid +  8) * 32]); \
    gl_lds16(asrc + (size_t)16*DIM + ko, &As[buf][(32*wid + 16) * 32]); \
    gl_lds16(asrc + (size_t)24*DIM + ko, &As[buf][(32*wid + 24) * 32]); \
    gl_lds16(bsrc_h + ko, &Bh[buf][(16 * wid) * 32]);                 \
    gl_lds16(bsrc_l + ko, &Bl[buf][(16 * wid) * 32]);                 \
  }

  f32x16 accE0 = {0,0,0,0, 0,0,0,0, 0,0,0,0, 0,0,0,0};   // experts 0..31
  f32x16 accE1 = {0,0,0,0, 0,0,0,0, 0,0,0,0, 0,0,0,0};   // experts 32..63

  // read-side constants
  const int akey = rc2 & 7;             // A row: 8 16B units (128B)
  const int bkey = rc2 & 3;             // B row: 4 16B units (64B)
  const int Arow = (32 * wid + rc2) * 32;
  const int Brow0 = rc2 * 32;           // experts 0..31
  const int Brow1 = (32 + rc2) * 32;    // experts 32..63

#define KSTEP(buf, kk) {                                                     \
    const int u0 = 4 * (kk) + 2 * q2;                                        \
    const float4 a0 = *(const float4*)(&As[buf][Arow + ((u0    ) ^ akey) * 4]); \
    const float4 a1 = *(const float4*)(&As[buf][Arow + ((u0 + 1) ^ akey) * 4]); \
    const int ub = ((2 * (kk) + q2) ^ bkey) * 8;                             \
    const f16x8 bh0 = *(const f16x8*)(&Bh[buf][Brow0 + ub]);                 \
    const f16x8 bl0 = *(const f16x8*)(&Bl[buf][Brow0 + ub]);                 \
    const f16x8 bh1 = *(const f16x8*)(&Bh[buf][Brow1 + ub]);                 \
    const f16x8 bl1 = *(const f16x8*)(&Bl[buf][Brow1 + ub]);                 \
    const f16x2 h0 = __builtin_amdgcn_cvt_pkrtz(a0.x, a0.y);                 \
    const f16x2 h1 = __builtin_amdgcn_cvt_pkrtz(a0.z, a0.w);                 \
    const f16x2 h2 = __builtin_amdgcn_cvt_pkrtz(a1.x, a1.y);                 \
    const f16x2 h3 = __builtin_amdgcn_cvt_pkrtz(a1.z, a1.w);                 \
    const f16x2 m0 = __builtin_amdgcn_cvt_pkrtz(a0.x - (float)h0[0],         \
                                                a0.y - (float)h0[1]);        \
    const f16x2 m1 = __builtin_amdgcn_cvt_pkrtz(a0.z - (float)h1[0],         \
                                                a0.w - (float)h1[1]);        \
    const f16x2 m2 = __builtin_amdgcn_cvt_pkrtz(a1.x - (float)h2[0],         \
                                                a1.y - (float)h2[1]);        \
    const f16x2 m3 = __builtin_amdgcn_cvt_pkrtz(a1.z - (float)h3[0],         \
                                                a1.w - (float)h3[1]);        \
    const f16x8 Ah = {h0[0],h0[1],h1[0],h1[1],h2[0],h2[1],h3[0],h3[1]};      \
    const f16x8 Am = {m0[0],m0[1],m1[0],m1[1],m2[0],m2[1],m3[0],m3[1]};      \
    accE0 = __builtin_amdgcn_mfma_f32_32x32x16_f16(Ah, bh0, accE0, 0, 0, 0); \
    accE1 = __builtin_amdgcn_mfma_f32_32x32x16_f16(Ah, bh1, accE1, 0, 0, 0); \
    accE0 = __builtin_amdgcn_mfma_f32_32x32x16_f16(Ah, bl0, accE0, 0, 0, 0); \
    accE1 = __builtin_amdgcn_mfma_f32_32x32x16_f16(Ah, bl1, accE1, 0, 0, 0); \
    accE0 = __builtin_amdgcn_mfma_f32_32x32x16_f16(Am, bh0, accE0, 0, 0, 0); \
    accE1 = __builtin_amdgcn_mfma_f32_32x32x16_f16(Am, bh1, accE1, 0, 0, 0); \
  }

#define COMP(buf) { KSTEP(buf, 0); KSTEP(buf, 1); }

  // prologue
  STAGE(0, 0);
  __syncthreads();

  // main loop: r7-proven 1-barrier-per-chunk double buffer
  for (int c = 0; c < NCH; c += 2) {
    if (c + 1 < NCH) STAGE(1, c + 1);
    COMP(0);
    __syncthreads();
    if (c + 2 < NCH) STAGE(0, c + 2);
    COMP(1);
    __syncthreads();
  }
#undef STAGE
#undef COMP
#undef KSTEP

  // write partial logits: D col = rc2 (expert within 32),
  // D row = (reg&3) + 8*(reg>>2) + 4*q2 (token within 32)  [m74-verified]
  float* P = partial + ((size_t)s * NTOK + tb + 32 * wid) * NEXP;
  #pragma unroll
  for (int reg = 0; reg < 16; ++reg) {
    const int row = (reg & 3) + 8 * (reg >> 2) + 4 * q2;
    P[(size_t)row * NEXP + rc2]      = accE0[reg];
    P[(size_t)row * NEXP + 32 + rc2] = accE1[reg];
  }
}

// ---- phase 2: reduce partials, softmax + top-2 ----
__global__ __launch_bounds__(256) void router_finish(
    const float* __restrict__ partial,
    float* __restrict__ out)
{
  const int t = blockIdx.x * 256 + threadIdx.x;

  float l[NEXP];
  const float* p0 = partial + (size_t)t * NEXP;
  #pragma unroll
  for (int qq = 0; qq < 16; ++qq) {
    const float4 v = *(const float4*)(p0 + qq * 4);
    l[qq*4+0] = v.x; l[qq*4+1] = v.y; l[qq*4+2] = v.z; l[qq*4+3] = v.w;
  }
  #pragma unroll
  for (int s = 1; s < KS; ++s) {
    const float* p = partial + ((size_t)s * NTOK + t) * NEXP;
    #pragma unroll
    for (int qq = 0; qq < 16; ++qq) {
      const float4 v = *(const float4*)(p + qq * 4);
      l[qq*4+0] += v.x; l[qq*4+1] += v.y; l[qq*4+2] += v.z; l[qq*4+3] += v.w;
    }
  }

  // top-2, lax.top_k tie-break (ascending scan with strict > keeps lower idx)
  float t1v = l[0]; int t1i = 0;
  float t2v = -INFINITY; int t2i = NEXP;
  #pragma unroll
  for (int e = 1; e < NEXP; ++e) {
    const float v = l[e];
    if (v > t1v) { t2v = t1v; t2i = t1i; t1v = v; t1i = e; }
    else if (v > t2v) { t2v = v; t2i = e; }
  }

  float ssum = 0.f;
  #pragma unroll
  for (int e = 0; e < NEXP; ++e) ssum += expf(l[e] - t1v);

  const float inv = 1.0f / ssum;
  out[t * 2 + 0] = inv;
  out[t * 2 + 1] = expf(t2v - t1v) * inv;
  out[2 * NTOK + t * 2 + 0] = (float)t1i;
  out[2 * NTOK + t * 2 + 1] = (float)t2i;
}

extern "C" void kernel_launch(void* const* d_in, const int* in_sizes, int n_in,
                              void* d_out, int out_size, void* d_ws, size_t ws_size,
                              hipStream_t stream) {
  const float* tokens = (const float*)d_in[0];
  const float* W      = (const float*)d_in[1];
  float* out          = (float*)d_out;

  __fp16* Wh = (__fp16*)d_ws;
  __fp16* Wl = Wh + (size_t)NEXP * DIM;
  float* partial = (float*)((char*)d_ws + (size_t)2 * NEXP * DIM * sizeof(__fp16));

  split_w<<<(NEXP * DIM) / 256, 256, 0, stream>>>(W, Wh, Wl);
  router_mfma<<<(NTOK / BM) * KS, 256, 0, stream>>>(tokens, Wh, Wl, partial);
  router_finish<<<NTOK / 256, 256, 0, stream>>>(partial, out);
}

// Round 15
// 75.120 us; speedup vs baseline: 1.4129x; 1.1058x over previous
//
#include <hip/hip_runtime.h>
#include <math.h>

#define NTOK 16384
#define DIM  4096
#define NEXP 64
#define KS   2                // K-split across blocks
#define KSL  (DIM / KS)       // 2048 k per slice
#define BK   64               // k per chunk
#define NCH  (KSL / BK)       // 32 chunks
#define BM   64               // tokens per block
#define KSF  4                // partial slices = KS * 2 (in-block k-halves)

typedef __fp16 f16x8  __attribute__((ext_vector_type(8)));
typedef __fp16 f16x2  __attribute__((ext_vector_type(2)));
typedef float  f32x16 __attribute__((ext_vector_type(16)));

__device__ __forceinline__ void gl_lds16(const void* g, void* l) {
  __builtin_amdgcn_global_load_lds(
      (const __attribute__((address_space(1))) void*)g,
      (__attribute__((address_space(3))) void*)l, 16, 0, 0);
}

// ---- prep: split W (fp32) into 2 fp16 planes (RNE hi, RNE residual) ----
__global__ __launch_bounds__(256) void split_w(
    const float* __restrict__ W,
    __fp16* __restrict__ Wh,
    __fp16* __restrict__ Wl)
{
  const int i = blockIdx.x * 256 + threadIdx.x;   // grid covers 64*4096
  const float w = W[i];
  const __fp16 h = (__fp16)w;                     // RNE
  const float r = w - (float)h;                   // exact
  Wh[i] = h;
  Wl[i] = (__fp16)r;                              // RNE, residual ~2^-24|w|
}

// ---- phase 1: r11 geometry, 8 waves/block: (token-half, expert-half,
// k-half) per wave; each wave writes its own k-partial slice ----
__global__ __launch_bounds__(512, 2) void router_mfma(
    const float* __restrict__ tokens,
    const __fp16* __restrict__ Wh,
    const __fp16* __restrict__ Wl,
    float* __restrict__ partial)   // [KSF][NTOK][NEXP]
{
  __shared__ float  As[2][BM * BK];     // 2 x 16 KB
  __shared__ __fp16 Bh[2][NEXP * BK];   // 2 x 8 KB
  __shared__ __fp16 Bl[2][NEXP * BK];   // 2 x 8 KB   -> 64 KB

  const int tid  = threadIdx.x;
  const int wid  = tid >> 6;            // 0..7
  const int lane = tid & 63;
  const int rc2  = lane & 31;           // MFMA row/col within 32
  const int q2   = lane >> 5;           // MFMA k-group
  const int kh   = wid & 1;             // k-half within chunk
  const int ec   = (wid >> 1) & 1;      // expert 32-half
  const int wr   = wid >> 2;            // token 32-half
  const int s    = blockIdx.x & (KS - 1);
  const int tb   = (blockIdx.x >> 1) * BM;   // block token base
  const int kbase = s * KSL;

  // ---- staging (pre-swizzled global, linear LDS dest): wave stages
  // A rows 8wid..8wid+7 (2 instrs x 4 rows x 256B) and B rows 8wid..+7
  // per plane (1 instr x 8 rows x 128B).
  const int r4 = lane >> 4, aj = lane & 15;        // A: 4 rows x 16 units
  const int ra0 = 8 * wid + r4;
  const int ra1 = 8 * wid + 4 + r4;
  const float* asrc0 = tokens + (size_t)(tb + ra0) * DIM + kbase
                       + ((aj ^ (ra0 & 15)) << 2);
  const float* asrc1 = tokens + (size_t)(tb + ra1) * DIM + kbase
                       + ((aj ^ (ra1 & 15)) << 2);
  const int e8 = lane >> 3, bj = lane & 7;         // B: 8 rows x 8 units
  const int rb = 8 * wid + e8;
  const size_t boff = (size_t)rb * DIM + kbase + ((bj ^ (rb & 7)) << 3);
  const __fp16* bsrc_h = Wh + boff;
  const __fp16* bsrc_l = Wl + boff;

#define STAGE(buf, c) {                                   \
    const int ko = (c) * BK;                              \
    gl_lds16(asrc0 + ko, &As[buf][(8 * wid) * BK]);       \
    gl_lds16(asrc1 + ko, &As[buf][(8 * wid + 4) * BK]);   \
    gl_lds16(bsrc_h + ko, &Bh[buf][(8 * wid) * BK]);      \
    gl_lds16(bsrc_l + ko, &Bl[buf][(8 * wid) * BK]);      \
  }

  f32x16 acc = {0,0,0,0, 0,0,0,0, 0,0,0,0, 0,0,0,0};

  // read-side constants
  const int akey = rc2 & 15;            // A row: 16 16B units (256B)
  const int bkey = rc2 & 7;             // B row: 8 16B units (128B)
  const int Arow = (32 * wr + rc2) * BK;
  const int Brow = (32 * ec + rc2) * BK;

#define KSTEP(buf, kk) {                                                     \
    const int ks_ = 2 * kh + (kk);                                           \
    const int u0 = 4 * ks_ + 2 * q2;                                         \
    const float4 a0 = *(const float4*)(&As[buf][Arow + ((u0    ) ^ akey) * 4]); \
    const float4 a1 = *(const float4*)(&As[buf][Arow + ((u0 + 1) ^ akey) * 4]); \
    const int ub = ((2 * ks_ + q2) ^ bkey) * 8;                              \
    const f16x8 bhv = *(const f16x8*)(&Bh[buf][Brow + ub]);                  \
    const f16x8 blv = *(const f16x8*)(&Bl[buf][Brow + ub]);                  \
    const f16x2 h0 = __builtin_amdgcn_cvt_pkrtz(a0.x, a0.y);                 \
    const f16x2 h1 = __builtin_amdgcn_cvt_pkrtz(a0.z, a0.w);                 \
    const f16x2 h2 = __builtin_amdgcn_cvt_pkrtz(a1.x, a1.y);                 \
    const f16x2 h3 = __builtin_amdgcn_cvt_pkrtz(a1.z, a1.w);                 \
    const f16x2 m0 = __builtin_amdgcn_cvt_pkrtz(a0.x - (float)h0[0],         \
                                                a0.y - (float)h0[1]);        \
    const f16x2 m1 = __builtin_amdgcn_cvt_pkrtz(a0.z - (float)h1[0],         \
                                                a0.w - (float)h1[1]);        \
    const f16x2 m2 = __builtin_amdgcn_cvt_pkrtz(a1.x - (float)h2[0],         \
                                                a1.y - (float)h2[1]);        \
    const f16x2 m3 = __builtin_amdgcn_cvt_pkrtz(a1.z - (float)h3[0],         \
                                                a1.w - (float)h3[1]);        \
    const f16x8 Ah = {h0[0],h0[1],h1[0],h1[1],h2[0],h2[1],h3[0],h3[1]};      \
    const f16x8 Am = {m0[0],m0[1],m1[0],m1[1],m2[0],m2[1],m3[0],m3[1]};      \
    acc = __builtin_amdgcn_mfma_f32_32x32x16_f16(Ah, bhv, acc, 0, 0, 0);     \
    acc = __builtin_amdgcn_mfma_f32_32x32x16_f16(Ah, blv, acc, 0, 0, 0);     \
    acc = __builtin_amdgcn_mfma_f32_32x32x16_f16(Am, bhv, acc, 0, 0, 0);     \
  }

#define COMP(buf) { KSTEP(buf, 0); KSTEP(buf, 1); }

  // prologue
  STAGE(0, 0);
  __syncthreads();

  // main loop: r7/r11-proven 1-barrier-per-chunk double buffer
  for (int c = 0; c < NCH; c += 2) {
    if (c + 1 < NCH) STAGE(1, c + 1);
    COMP(0);
    __syncthreads();
    if (c + 2 < NCH) STAGE(0, c + 2);
    COMP(1);
    __syncthreads();
  }
#undef STAGE
#undef COMP
#undef KSTEP

  // write k-partial logits to slice (2s+kh): D col = rc2 (expert in 32),
  // D row = (reg&3) + 8*(reg>>2) + 4*q2 (token in 32)  [m74-verified]
  float* P = partial + ((size_t)(2 * s + kh) * NTOK + tb + 32 * wr) * NEXP
             + 32 * ec;
  #pragma unroll
  for (int reg = 0; reg < 16; ++reg) {
    const int row = (reg & 3) + 8 * (reg >> 2) + 4 * q2;
    P[(size_t)row * NEXP + rc2] = acc[reg];
  }
}

// ---- phase 2: reduce 4 partial slices, softmax + top-2 ----
__global__ __launch_bounds__(256) void router_finish(
    const float* __restrict__ partial,
    float* __restrict__ out)
{
  const int t = blockIdx.x * 256 + threadIdx.x;

  float l[NEXP];
  const float* p0 = partial + (size_t)t * NEXP;
  #pragma unroll
  for (int qq = 0; qq < 16; ++qq) {
    const float4 v = *(const float4*)(p0 + qq * 4);
    l[qq*4+0] = v.x; l[qq*4+1] = v.y; l[qq*4+2] = v.z; l[qq*4+3] = v.w;
  }
  #pragma unroll
  for (int s = 1; s < KSF; ++s) {
    const float* p = partial + ((size_t)s * NTOK + t) * NEXP;
    #pragma unroll
    for (int qq = 0; qq < 16; ++qq) {
      const float4 v = *(const float4*)(p + qq * 4);
      l[qq*4+0] += v.x; l[qq*4+1] += v.y; l[qq*4+2] += v.z; l[qq*4+3] += v.w;
    }
  }

  // top-2, lax.top_k tie-break (ascending scan with strict > keeps lower idx)
  float t1v = l[0]; int t1i = 0;
  float t2v = -INFINITY; int t2i = NEXP;
  #pragma unroll
  for (int e = 1; e < NEXP; ++e) {
    const float v = l[e];
    if (v > t1v) { t2v = t1v; t2i = t1i; t1v = v; t1i = e; }
    else if (v > t2v) { t2v = v; t2i = e; }
  }

  float ssum = 0.f;
  #pragma unroll
  for (int e = 0; e < NEXP; ++e) ssum += expf(l[e] - t1v);

  const float inv = 1.0f / ssum;
  out[t * 2 + 0] = inv;
  out[t * 2 + 1] = expf(t2v - t1v) * inv;
  out[2 * NTOK + t * 2 + 0] = (float)t1i;
  out[2 * NTOK + t * 2 + 1] = (float)t2i;
}

extern "C" void kernel_launch(void* const* d_in, const int* in_sizes, int n_in,
                              void* d_out, int out_size, void* d_ws, size_t ws_size,
                              hipStream_t stream) {
  const float* tokens = (const float*)d_in[0];
  const float* W      = (const float*)d_in[1];
  float* out          = (float*)d_out;

  __fp16* Wh = (__fp16*)d_ws;
  __fp16* Wl = Wh + (size_t)NEXP * DIM;
  float* partial = (float*)((char*)d_ws + (size_t)2 * NEXP * DIM * sizeof(__fp16));

  split_w<<<(NEXP * DIM) / 256, 256, 0, stream>>>(W, Wh, Wl);
  router_mfma<<<(NTOK / BM) * KS, 512, 0, stream>>>(tokens, Wh, Wl, partial);
  router_finish<<<NTOK / 256, 256, 0, stream>>>(partial, out);
}

// Round 16
// 70.814 us; speedup vs baseline: 1.4988x; 1.0608x over previous
//
#include <hip/hip_runtime.h>
#include <math.h>

#define NTOK 16384
#define DIM  4096
#define NEXP 64
#define KS   2                // K-split factor
#define KSL  (DIM / KS)       // 2048 k per slice
#define BK   64               // k per chunk
#define NCH  (KSL / BK)       // 32 chunks
#define BM   64               // tokens per block (2x2 waves of 32x32)

typedef __fp16 f16x8  __attribute__((ext_vector_type(8)));
typedef __fp16 f16x4  __attribute__((ext_vector_type(4)));
typedef __fp16 f16x2  __attribute__((ext_vector_type(2)));
typedef float  f32x16 __attribute__((ext_vector_type(16)));

__device__ __forceinline__ void gl_lds16(const void* g, void* l) {
  __builtin_amdgcn_global_load_lds(
      (const __attribute__((address_space(1))) void*)g,
      (__attribute__((address_space(3))) void*)l, 16, 0, 0);
}

// ---- prep: split W (fp32) into 2 fp16 planes, vectorized x4 ----
__global__ __launch_bounds__(256) void split_w(
    const float* __restrict__ W,
    __fp16* __restrict__ Wh,
    __fp16* __restrict__ Wl)
{
  const int i = (blockIdx.x * 256 + threadIdx.x) * 4;   // covers 64*4096
  const float4 w = *(const float4*)(W + i);
  f16x4 h, l;
  h[0] = (__fp16)w.x; h[1] = (__fp16)w.y; h[2] = (__fp16)w.z; h[3] = (__fp16)w.w;
  l[0] = (__fp16)(w.x - (float)h[0]);
  l[1] = (__fp16)(w.y - (float)h[1]);
  l[2] = (__fp16)(w.z - (float)h[2]);
  l[3] = (__fp16)(w.w - (float)h[3]);
  *(f16x4*)(Wh + i) = h;
  *(f16x4*)(Wl + i) = l;
}

// ---- phase 1: 32x32x16 MFMA, gl_lds double-buffer, r7 sync structure ----
// (r11 champion datapath, verbatim)
__global__ __launch_bounds__(256, 2) void router_mfma(
    const float* __restrict__ tokens,
    const __fp16* __restrict__ Wh,
    const __fp16* __restrict__ Wl,
    float* __restrict__ partial)   // [KS][NTOK][NEXP]
{
  __shared__ float  As[2][BM * BK];     // 2 x 16 KB
  __shared__ __fp16 Bh[2][NEXP * BK];   // 2 x 8 KB
  __shared__ __fp16 Bl[2][NEXP * BK];   // 2 x 8 KB   -> 64 KB

  const int tid  = threadIdx.x;
  const int wid  = tid >> 6;
  const int lane = tid & 63;
  const int rc2  = lane & 31;           // MFMA row/col within 32
  const int q2   = lane >> 5;           // k-half
  const int wr   = wid >> 1;            // token 32-half
  const int ec   = wid & 1;             // expert 32-half
  const int s    = blockIdx.x & (KS - 1);
  const int tb   = (blockIdx.x >> 1) * BM;   // block token base
  const int kbase = s * KSL;

  // ---- staging sources (pre-swizzled global, linear LDS dest: G21) ----
  // A: wave stages rows 16*wid+4i+(lane>>4); row=64 f32=16 units; key=r&15
  const int l16 = lane >> 4;            // 0..3
  const int aj  = lane & 15;            // 16B unit within row
  const float* ap0 = tokens + (size_t)(tb + 16*wid +  0 + l16) * DIM + kbase + ((aj ^ ( 0 + l16)) << 2);
  const float* ap1 = tokens + (size_t)(tb + 16*wid +  4 + l16) * DIM + kbase + ((aj ^ ( 4 + l16)) << 2);
  const float* ap2 = tokens + (size_t)(tb + 16*wid +  8 + l16) * DIM + kbase + ((aj ^ ( 8 + l16)) << 2);
  const float* ap3 = tokens + (size_t)(tb + 16*wid + 12 + l16) * DIM + kbase + ((aj ^ (12 + l16)) << 2);
  // B: wave stages experts 16*wid+8i+(lane>>3); row=64 f16=8 units; key=e&7
  const int l8 = lane >> 3;             // 0..7
  const int bj = lane & 7;              // 16B unit within row
  const size_t bo0 = (size_t)(16*wid + 0 + l8) * DIM + kbase + ((bj ^ l8) << 3);
  const size_t bo1 = (size_t)(16*wid + 8 + l8) * DIM + kbase + ((bj ^ l8) << 3);
  const __fp16* bh0s = Wh + bo0; const __fp16* bh1s = Wh + bo1;
  const __fp16* bl0s = Wl + bo0; const __fp16* bl1s = Wl + bo1;

#define STAGE(buf, c) {                                          \
    const int ko = (c) * BK;                                     \
    gl_lds16(ap0 + ko, &As[buf][(16 * wid +  0) * BK]);          \
    gl_lds16(ap1 + ko, &As[buf][(16 * wid +  4) * BK]);          \
    gl_lds16(ap2 + ko, &As[buf][(16 * wid +  8) * BK]);          \
    gl_lds16(ap3 + ko, &As[buf][(16 * wid + 12) * BK]);          \
    gl_lds16(bh0s + ko, &Bh[buf][(16 * wid + 0) * BK]);          \
    gl_lds16(bh1s + ko, &Bh[buf][(16 * wid + 8) * BK]);          \
    gl_lds16(bl0s + ko, &Bl[buf][(16 * wid + 0) * BK]);          \
    gl_lds16(bl1s + ko, &Bl[buf][(16 * wid + 8) * BK]);          \
  }

  f32x16 acc = {0,0,0,0, 0,0,0,0, 0,0,0,0, 0,0,0,0};

  // read-side constants
  const int akey = rc2 & 15;
  const int bkey = rc2 & 7;
  const int Arow = (32 * wr + rc2) * BK;
  const int Brow = (32 * ec + rc2) * BK;

#define KSTEP(buf, kk) {                                                     \
    const int u0 = 4 * (kk) + 2 * q2;                                        \
    const float4 a0 = *(const float4*)(&As[buf][Arow + ((u0    ) ^ akey) * 4]); \
    const float4 a1 = *(const float4*)(&As[buf][Arow + ((u0 + 1) ^ akey) * 4]); \
    const int ub = ((2 * (kk) + q2) ^ bkey) * 8;                             \
    const f16x8 bhv = *(const f16x8*)(&Bh[buf][Brow + ub]);                  \
    const f16x8 blv = *(const f16x8*)(&Bl[buf][Brow + ub]);                  \
    const f16x2 h0 = __builtin_amdgcn_cvt_pkrtz(a0.x, a0.y);                 \
    const f16x2 h1 = __builtin_amdgcn_cvt_pkrtz(a0.z, a0.w);                 \
    const f16x2 h2 = __builtin_amdgcn_cvt_pkrtz(a1.x, a1.y);                 \
    const f16x2 h3 = __builtin_amdgcn_cvt_pkrtz(a1.z, a1.w);                 \
    const f16x2 m0 = __builtin_amdgcn_cvt_pkrtz(a0.x - (float)h0[0],         \
                                                a0.y - (float)h0[1]);        \
    const f16x2 m1 = __builtin_amdgcn_cvt_pkrtz(a0.z - (float)h1[0],         \
                                                a0.w - (float)h1[1]);        \
    const f16x2 m2 = __builtin_amdgcn_cvt_pkrtz(a1.x - (float)h2[0],         \
                                                a1.y - (float)h2[1]);        \
    const f16x2 m3 = __builtin_amdgcn_cvt_pkrtz(a1.z - (float)h3[0],         \
                                                a1.w - (float)h3[1]);        \
    const f16x8 Ah = {h0[0],h0[1],h1[0],h1[1],h2[0],h2[1],h3[0],h3[1]};      \
    const f16x8 Am = {m0[0],m0[1],m1[0],m1[1],m2[0],m2[1],m3[0],m3[1]};      \
    acc = __builtin_amdgcn_mfma_f32_32x32x16_f16(Ah, bhv, acc, 0, 0, 0);     \
    acc = __builtin_amdgcn_mfma_f32_32x32x16_f16(Ah, blv, acc, 0, 0, 0);     \
    acc = __builtin_amdgcn_mfma_f32_32x32x16_f16(Am, bhv, acc, 0, 0, 0);     \
  }

#define COMP(buf) { KSTEP(buf, 0); KSTEP(buf, 1); KSTEP(buf, 2); KSTEP(buf, 3); }

  // prologue
  STAGE(0, 0);
  __syncthreads();

  // main loop: r7-proven 1-barrier-per-chunk double buffer
  for (int c = 0; c < NCH; c += 2) {
    if (c + 1 < NCH) STAGE(1, c + 1);
    COMP(0);
    __syncthreads();
    if (c + 2 < NCH) STAGE(0, c + 2);
    COMP(1);
    __syncthreads();
  }
#undef STAGE
#undef COMP
#undef KSTEP

  // write partial logits: D col = rc2 (expert within 32),
  // D row = (reg&3) + 8*(reg>>2) + 4*q2 (token within 32)  [m74-verified]
  float* P = partial + ((size_t)s * NTOK + tb + 32 * wr) * NEXP + 32 * ec;
  #pragma unroll
  for (int reg = 0; reg < 16; ++reg) {
    const int row = (reg & 3) + 8 * (reg >> 2) + 4 * q2;
    P[(size_t)row * NEXP + rc2] = acc[reg];
  }
}

// ---- phase 2: reduce partials, softmax + top-2 ----
__global__ __launch_bounds__(64) void router_finish(
    const float* __restrict__ partial,
    float* __restrict__ out)
{
  const int t = blockIdx.x * 64 + threadIdx.x;

  float l[NEXP];
  const float* p0 = partial + (size_t)t * NEXP;
  #pragma unroll
  for (int qq = 0; qq < 16; ++qq) {
    const float4 v = *(const float4*)(p0 + qq * 4);
    l[qq*4+0] = v.x; l[qq*4+1] = v.y; l[qq*4+2] = v.z; l[qq*4+3] = v.w;
  }
  #pragma unroll
  for (int s = 1; s < KS; ++s) {
    const float* p = partial + ((size_t)s * NTOK + t) * NEXP;
    #pragma unroll
    for (int qq = 0; qq < 16; ++qq) {
      const float4 v = *(const float4*)(p + qq * 4);
      l[qq*4+0] += v.x; l[qq*4+1] += v.y; l[qq*4+2] += v.z; l[qq*4+3] += v.w;
    }
  }

  // top-2, lax.top_k tie-break (ascending scan with strict > keeps lower idx)
  float t1v = l[0]; int t1i = 0;
  float t2v = -INFINITY; int t2i = NEXP;
  #pragma unroll
  for (int e = 1; e < NEXP; ++e) {
    const float v = l[e];
    if (v > t1v) { t2v = t1v; t2i = t1i; t1v = v; t1i = e; }
    else if (v > t2v) { t2v = v; t2i = e; }
  }

  float ssum = 0.f;
  #pragma unroll
  for (int e = 0; e < NEXP; ++e) ssum += expf(l[e] - t1v);

  const float inv = 1.0f / ssum;
  out[t * 2 + 0] = inv;
  out[t * 2 + 1] = expf(t2v - t1v) * inv;
  out[2 * NTOK + t * 2 + 0] = (float)t1i;
  out[2 * NTOK + t * 2 + 1] = (float)t2i;
}

extern "C" void kernel_launch(void* const* d_in, const int* in_sizes, int n_in,
                              void* d_out, int out_size, void* d_ws, size_t ws_size,
                              hipStream_t stream) {
  const float* tokens = (const float*)d_in[0];
  const float* W      = (const float*)d_in[1];
  float* out          = (float*)d_out;

  __fp16* Wh = (__fp16*)d_ws;
  __fp16* Wl = Wh + (size_t)NEXP * DIM;
  float* partial = (float*)((char*)d_ws + (size_t)2 * NEXP * DIM * sizeof(__fp16));

  split_w<<<(NEXP * DIM) / 1024, 256, 0, stream>>>(W, Wh, Wl);
  router_mfma<<<(NTOK / BM) * KS, 256, 0, stream>>>(tokens, Wh, Wl, partial);
  router_finish<<<NTOK / 64, 64, 0, stream>>>(partial, out);
}

// Round 17
// 69.811 us; speedup vs baseline: 1.5204x; 1.0144x over previous
//
#include <hip/hip_runtime.h>
#include <math.h>

#define NTOK 16384
#define DIM  4096
#define NEXP 64
#define KHL  (DIM / 2)        // k per half-group
#define BK   64               // k per chunk
#define NCH  (KHL / BK)       // 32 chunks per group
#define BM   64               // tokens per block

typedef __fp16 f16x8  __attribute__((ext_vector_type(8)));
typedef __fp16 f16x4  __attribute__((ext_vector_type(4)));
typedef __fp16 f16x2  __attribute__((ext_vector_type(2)));
typedef float  f32x16 __attribute__((ext_vector_type(16)));

__device__ __forceinline__ void gl_lds16(const void* g, void* l) {
  __builtin_amdgcn_global_load_lds(
      (const __attribute__((address_space(1))) void*)g,
      (__attribute__((address_space(3))) void*)l, 16, 0, 0);
}

// ---- prep: split W (fp32) into 2 fp16 planes, vectorized x4 ----
__global__ __launch_bounds__(256) void split_w(
    const float* __restrict__ W,
    __fp16* __restrict__ Wh,
    __fp16* __restrict__ Wl)
{
  const int i = (blockIdx.x * 256 + threadIdx.x) * 4;   // covers 64*4096
  const float4 w = *(const float4*)(W + i);
  f16x4 h, l;
  h[0] = (__fp16)w.x; h[1] = (__fp16)w.y; h[2] = (__fp16)w.z; h[3] = (__fp16)w.w;
  l[0] = (__fp16)(w.x - (float)h[0]);
  l[1] = (__fp16)(w.y - (float)h[1]);
  l[2] = (__fp16)(w.z - (float)h[2]);
  l[3] = (__fp16)(w.w - (float)h[3]);
  *(f16x4*)(Wh + i) = h;
  *(f16x4*)(Wl + i) = l;
}

// ---- fused router: 2 k-half groups x 4 waves, champion datapath per wave;
// in-LDS cross-half reduction + top-2 + softmax epilogue, direct output ----
__global__ __launch_bounds__(512, 1) void router_fused(
    const float* __restrict__ tokens,
    const __fp16* __restrict__ Wh,
    const __fp16* __restrict__ Wl,
    float* __restrict__ out)
{
  __shared__ float  As[2][2][BM * BK];     // [kh][buf]: 64 KB
  __shared__ __fp16 Bh[2][2][NEXP * BK];   // 32 KB
  __shared__ __fp16 Bl[2][2][NEXP * BK];   // 32 KB  -> 128 KB total

  const int tid  = threadIdx.x;
  const int wid  = tid >> 6;            // 0..7
  const int lane = tid & 63;
  const int kh   = wid >> 2;            // k-half group
  const int gw   = wid & 3;             // wave within group (r11's wid role)
  const int rc2  = lane & 31;           // MFMA row/col within 32
  const int q2   = lane >> 5;           // k-half within MFMA
  const int wr   = gw >> 1;             // token 32-half
  const int ec   = gw & 1;              // expert 32-half
  const int tb   = blockIdx.x * BM;     // block token base
  const int kbase = kh * KHL;

  // ---- staging sources (pre-swizzled global, linear LDS dest: G21) ----
  // A: wave stages rows 16*gw+4i+(lane>>4); row=64 f32=16 units; key=r&15
  const int l16 = lane >> 4;            // 0..3
  const int aj  = lane & 15;            // 16B unit within row
  const float* ap0 = tokens + (size_t)(tb + 16*gw +  0 + l16) * DIM + kbase + ((aj ^ ( 0 + l16)) << 2);
  const float* ap1 = tokens + (size_t)(tb + 16*gw +  4 + l16) * DIM + kbase + ((aj ^ ( 4 + l16)) << 2);
  const float* ap2 = tokens + (size_t)(tb + 16*gw +  8 + l16) * DIM + kbase + ((aj ^ ( 8 + l16)) << 2);
  const float* ap3 = tokens + (size_t)(tb + 16*gw + 12 + l16) * DIM + kbase + ((aj ^ (12 + l16)) << 2);
  // B: wave stages experts 16*gw+8i+(lane>>3); row=64 f16=8 units; key=e&7
  const int l8 = lane >> 3;             // 0..7
  const int bj = lane & 7;              // 16B unit within row
  const size_t bo0 = (size_t)(16*gw + 0 + l8) * DIM + kbase + ((bj ^ l8) << 3);
  const size_t bo1 = (size_t)(16*gw + 8 + l8) * DIM + kbase + ((bj ^ l8) << 3);
  const __fp16* bh0s = Wh + bo0; const __fp16* bh1s = Wh + bo1;
  const __fp16* bl0s = Wl + bo0; const __fp16* bl1s = Wl + bo1;

#define STAGE(buf, c) {                                          \
    const int ko = (c) * BK;                                     \
    gl_lds16(ap0 + ko, &As[kh][buf][(16 * gw +  0) * BK]);       \
    gl_lds16(ap1 + ko, &As[kh][buf][(16 * gw +  4) * BK]);       \
    gl_lds16(ap2 + ko, &As[kh][buf][(16 * gw +  8) * BK]);       \
    gl_lds16(ap3 + ko, &As[kh][buf][(16 * gw + 12) * BK]);       \
    gl_lds16(bh0s + ko, &Bh[kh][buf][(16 * gw + 0) * BK]);       \
    gl_lds16(bh1s + ko, &Bh[kh][buf][(16 * gw + 8) * BK]);       \
    gl_lds16(bl0s + ko, &Bl[kh][buf][(16 * gw + 0) * BK]);       \
    gl_lds16(bl1s + ko, &Bl[kh][buf][(16 * gw + 8) * BK]);       \
  }

  f32x16 acc = {0,0,0,0, 0,0,0,0, 0,0,0,0, 0,0,0,0};

  // read-side constants
  const int akey = rc2 & 15;
  const int bkey = rc2 & 7;
  const int Arow = (32 * wr + rc2) * BK;
  const int Brow = (32 * ec + rc2) * BK;

#define KSTEP(buf, kk) {                                                     \
    const int u0 = 4 * (kk) + 2 * q2;                                        \
    const float4 a0 = *(const float4*)(&As[kh][buf][Arow + ((u0    ) ^ akey) * 4]); \
    const float4 a1 = *(const float4*)(&As[kh][buf][Arow + ((u0 + 1) ^ akey) * 4]); \
    const int ub = ((2 * (kk) + q2) ^ bkey) * 8;                             \
    const f16x8 bhv = *(const f16x8*)(&Bh[kh][buf][Brow + ub]);              \
    const f16x8 blv = *(const f16x8*)(&Bl[kh][buf][Brow + ub]);              \
    const f16x2 h0 = __builtin_amdgcn_cvt_pkrtz(a0.x, a0.y);                 \
    const f16x2 h1 = __builtin_amdgcn_cvt_pkrtz(a0.z, a0.w);                 \
    const f16x2 h2 = __builtin_amdgcn_cvt_pkrtz(a1.x, a1.y);                 \
    const f16x2 h3 = __builtin_amdgcn_cvt_pkrtz(a1.z, a1.w);                 \
    const f16x2 m0 = __builtin_amdgcn_cvt_pkrtz(a0.x - (float)h0[0],         \
                                                a0.y - (float)h0[1]);        \
    const f16x2 m1 = __builtin_amdgcn_cvt_pkrtz(a0.z - (float)h1[0],         \
                                                a0.w - (float)h1[1]);        \
    const f16x2 m2 = __builtin_amdgcn_cvt_pkrtz(a1.x - (float)h2[0],         \
                                                a1.y - (float)h2[1]);        \
    const f16x2 m3 = __builtin_amdgcn_cvt_pkrtz(a1.z - (float)h3[0],         \
                                                a1.w - (float)h3[1]);        \
    const f16x8 Ah = {h0[0],h0[1],h1[0],h1[1],h2[0],h2[1],h3[0],h3[1]};      \
    const f16x8 Am = {m0[0],m0[1],m1[0],m1[1],m2[0],m2[1],m3[0],m3[1]};      \
    acc = __builtin_amdgcn_mfma_f32_32x32x16_f16(Ah, bhv, acc, 0, 0, 0);     \
    acc = __builtin_amdgcn_mfma_f32_32x32x16_f16(Ah, blv, acc, 0, 0, 0);     \
    acc = __builtin_amdgcn_mfma_f32_32x32x16_f16(Am, bhv, acc, 0, 0, 0);     \
  }

#define COMP(buf) { KSTEP(buf, 0); KSTEP(buf, 1); KSTEP(buf, 2); KSTEP(buf, 3); }

  // prologue
  STAGE(0, 0);
  __syncthreads();

  // main loop: champion 1-barrier-per-chunk double buffer (per group)
  for (int c = 0; c < NCH; c += 2) {
    if (c + 1 < NCH) STAGE(1, c + 1);
    COMP(0);
    __syncthreads();
    if (c + 2 < NCH) STAGE(0, c + 2);
    COMP(1);
    __syncthreads();
  }
#undef STAGE
#undef COMP
#undef KSTEP

  // ---- epilogue: in-LDS cross-half reduce, then top-2 + softmax ----
  // Ls[64][65] (padded) aliases the A buffers (4160 floats < 16384).
  float* Ls = &As[0][0][0];
  // (last barrier of the loop already fenced all buffer readers)
  #pragma unroll
  for (int reg = 0; reg < 16; ++reg) {
    const int row = (reg & 3) + 8 * (reg >> 2) + 4 * q2;   // m74 D-layout
    if (kh == 0)
      Ls[(32 * wr + row) * 65 + 32 * ec + rc2] = acc[reg];
  }
  __syncthreads();
  #pragma unroll
  for (int reg = 0; reg < 16; ++reg) {
    const int row = (reg & 3) + 8 * (reg >> 2) + 4 * q2;
    if (kh == 1)
      Ls[(32 * wr + row) * 65 + 32 * ec + rc2] += acc[reg];
  }
  __syncthreads();

  if (tid < 64) {
    const int t = tb + tid;
    float l[NEXP];
    #pragma unroll
    for (int e = 0; e < NEXP; ++e) l[e] = Ls[tid * 65 + e];

    // top-2, lax.top_k tie-break (ascending scan, strict > keeps lower idx)
    float t1v = l[0]; int t1i = 0;
    float t2v = -INFINITY; int t2i = NEXP;
    #pragma unroll
    for (int e = 1; e < NEXP; ++e) {
      const float v = l[e];
      if (v > t1v) { t2v = t1v; t2i = t1i; t1v = v; t1i = e; }
      else if (v > t2v) { t2v = v; t2i = e; }
    }
    float ssum = 0.f;
    #pragma unroll
    for (int e = 0; e < NEXP; ++e) ssum += expf(l[e] - t1v);

    const float inv = 1.0f / ssum;
    out[t * 2 + 0] = inv;
    out[t * 2 + 1] = expf(t2v - t1v) * inv;
    out[2 * NTOK + t * 2 + 0] = (float)t1i;
    out[2 * NTOK + t * 2 + 1] = (float)t2i;
  }
}

extern "C" void kernel_launch(void* const* d_in, const int* in_sizes, int n_in,
                              void* d_out, int out_size, void* d_ws, size_t ws_size,
                              hipStream_t stream) {
  const float* tokens = (const float*)d_in[0];
  const float* W      = (const float*)d_in[1];
  float* out          = (float*)d_out;

  __fp16* Wh = (__fp16*)d_ws;
  __fp16* Wl = Wh + (size_t)NEXP * DIM;

  split_w<<<(NEXP * DIM) / 1024, 256, 0, stream>>>(W, Wh, Wl);
  router_fused<<<NTOK / BM, 512, 0, stream>>>(tokens, Wh, Wl, out);
}